// Round 5
// baseline (226.423 us; speedup 1.0000x reference)
//
#include <hip/hip_runtime.h>

// NMS 2D, 3x3 window, replicate padding, center excluded, max seeded with 0.
// x: (8, 64, 256, 256) fp32.  out[p] = x[p] if x[p] > max(0, 8 neighbors) else 0.
//
// R12 = R8 structure (4 rows/wave, straight-line) WITHOUT the XCD swizzle.
// Session history (kernel-only = bench - 2 x 80.4 us harness fills):
//   R7  (1 row/thread, swizzle)              65.8 us
//   R8  (4 rows/thread, swizzle)             68.9 us   "neutral" -- CONFOUNDED
//   R9  (R8 + nt stores)                     79.6 us   regressed
//   R10 (16-row pipelined strip)             83.5 us   regressed
//   R11 (R7, no swizzle)                     60.2 us   <- best; swizzle costs
//        ~5.6 us in the L3-fit regime (guide m160 mechanism confirmed)
// R8's demand-halving test inherited the swizzle penalty -- rerun it clean.
// Theory under test: kernel is cache-hierarchy service-rate bound (CU-side
// demand 3x134 read + 134 write = 536 MB in 60 us = 8.9 TB/s). 4 rows/wave
// cuts read demand 3.0x -> 1.5x (335 MB total). If service-rate-bound:
// ~50-55 us. If latency/queueing-bound: neutral -> declare roofline with R11.
// Straight-line shape: all 6 loads issued before any store (vmcnt queue
// never makes a load-wait drain stores).

#define NMS_H 256
#define NMS_W 256
#define PLANE (NMS_H * NMS_W)
#define GRID_BLOCKS 8192   // 512 planes * 16 row-groups (16 rows, 4 waves)

typedef float f4_t __attribute__((ext_vector_type(4)));

struct HV {
    float4 h;   // horizontal max-of-3 per pixel (includes center)
    float4 lr;  // horizontal max of left+right only (center excluded)
};

__device__ __forceinline__ HV rowmax(const float4 v, const int tx) {
    float l = __shfl_up(v.w, 1, 64);    // last elem of lane tx-1
    float r = __shfl_down(v.x, 1, 64);  // first elem of lane tx+1
    if (tx == 0)  l = v.x;              // replicate pad left edge
    if (tx == 63) r = v.w;              // replicate pad right edge
    HV o;
    o.h.x = fmaxf(l,   fmaxf(v.x, v.y));
    o.h.y = fmaxf(v.x, fmaxf(v.y, v.z));
    o.h.z = fmaxf(v.y, fmaxf(v.z, v.w));
    o.h.w = fmaxf(v.z, fmaxf(v.w, r));
    o.lr.x = fmaxf(l,   v.y);
    o.lr.y = fmaxf(v.x, v.z);
    o.lr.z = fmaxf(v.y, v.w);
    o.lr.w = fmaxf(v.z, r);
    return o;
}

// m = max(0, h(row above), h(row below), lr(own row)); keep vc if strictly greater.
__device__ __forceinline__ f4_t nmspick(const float4 vc, const float4 ha,
                                        const float4 hb, const float4 lrc) {
    f4_t o;
    float m;
    m = fmaxf(0.0f, fmaxf(fmaxf(ha.x, hb.x), lrc.x)); o.x = (vc.x > m) ? vc.x : 0.0f;
    m = fmaxf(0.0f, fmaxf(fmaxf(ha.y, hb.y), lrc.y)); o.y = (vc.y > m) ? vc.y : 0.0f;
    m = fmaxf(0.0f, fmaxf(fmaxf(ha.z, hb.z), lrc.z)); o.z = (vc.z > m) ? vc.z : 0.0f;
    m = fmaxf(0.0f, fmaxf(fmaxf(ha.w, hb.w), lrc.w)); o.w = (vc.w > m) ? vc.w : 0.0f;
    return o;
}

__global__ __launch_bounds__(256, 4) void nms2d_kernel(const float* __restrict__ x,
                                                       float* __restrict__ out) {
    // No XCD swizzle (R11 lesson: costs ~5.6 us when input is L3-fit).
    const int logical = blockIdx.x;

    const int plane_idx = logical >> 4;        // 512 planes
    const int rg        = logical & 15;        // 16 row-groups of 16 rows
    const int tx        = threadIdx.x & 63;    // float4 column-group
    const int R         = rg * 16 + (threadIdx.x >> 6) * 4;  // wave's first row
    const int col4      = tx * 4;

    const float* pl = x + (size_t)plane_idx * PLANE + col4;

    // 6 independent clamped row loads -- the thread's entire read set,
    // all issued before any compute or store.
    const int rm = max(R - 1, 0);              // only clamps when R == 0
    const int rp = min(R + 4, NMS_H - 1);      // only clamps when R == 252
    const float4 vm = *reinterpret_cast<const float4*>(pl + rm      * NMS_W);
    const float4 v0 = *reinterpret_cast<const float4*>(pl + (R + 0) * NMS_W);
    const float4 v1 = *reinterpret_cast<const float4*>(pl + (R + 1) * NMS_W);
    const float4 v2 = *reinterpret_cast<const float4*>(pl + (R + 2) * NMS_W);
    const float4 v3 = *reinterpret_cast<const float4*>(pl + (R + 3) * NMS_W);
    const float4 vp = *reinterpret_cast<const float4*>(pl + rp      * NMS_W);

    // One rowmax per loaded row, shared by all outputs that touch it.
    // (hm.lr / hp.lr are dead and get DCE'd.)
    const HV hm = rowmax(vm, tx);
    const HV h0 = rowmax(v0, tx);
    const HV h1 = rowmax(v1, tx);
    const HV h2 = rowmax(v2, tx);
    const HV h3 = rowmax(v3, tx);
    const HV hp = rowmax(vp, tx);

    float* po = out + (size_t)plane_idx * PLANE + col4;
    *reinterpret_cast<f4_t*>(po + (R + 0) * NMS_W) = nmspick(v0, hm.h, h1.h, h0.lr);
    *reinterpret_cast<f4_t*>(po + (R + 1) * NMS_W) = nmspick(v1, h0.h, h2.h, h1.lr);
    *reinterpret_cast<f4_t*>(po + (R + 2) * NMS_W) = nmspick(v2, h1.h, h3.h, h2.lr);
    *reinterpret_cast<f4_t*>(po + (R + 3) * NMS_W) = nmspick(v3, h2.h, hp.h, h3.lr);
}

extern "C" void kernel_launch(void* const* d_in, const int* in_sizes, int n_in,
                              void* d_out, int out_size, void* d_ws, size_t ws_size,
                              hipStream_t stream) {
    const float* x = (const float*)d_in[0];
    float* out = (float*)d_out;

    // One wave per 4 output rows: 512 planes x 16 row-groups = 8192 blocks.
    dim3 block(256);
    dim3 grid(GRID_BLOCKS);
    nms2d_kernel<<<grid, block, 0, stream>>>(x, out);
}

// Round 6
// 219.668 us; speedup vs baseline: 1.0308x; 1.0308x over previous
//
#include <hip/hip_runtime.h>

// NMS 2D, 3x3 window, replicate padding, center excluded, max seeded with 0.
// x: (8, 64, 256, 256) fp32.  out[p] = x[p] if x[p] > max(0, 8 neighbors) else 0.
//
// R13 = R11 verbatim (best measured: 221.0 us bench / ~60.2 us kernel).
// FINAL. Session ladder (kernel-only = bench - 2 x ~80.5 us harness fills):
//   R11 (1 row/thread, no swizzle, 32768 blk)  60.2 us  <- best
//   R7  (same + XCD swizzle)                   65.8 us  swizzle costs ~5.6 us
//        when input is L3-fit (guide m160 mechanism, confirmed here)
//   R12 (4 rows/wave, no swizzle)              64.6 us  demand-halving loses
//        to TLP loss (unconfounded A/B)
//   R8/R9/R10 (issue-halving / nt stores / pipelined strip)  68.9-83.5 us
// Law of this kernel: perf tracks wave count monotonically; nothing is
// saturated (VALU<=11%, HBM<=31%, DS=0, occ<=72%) -- latency/queueing-bound
// halo fan-out. Max TLP + default dispatch + plain float4 loads/stores wins.

#define NMS_H 256
#define NMS_W 256
#define PLANE (NMS_H * NMS_W)

typedef float f4_t __attribute__((ext_vector_type(4)));

struct HV {
    float4 h;   // horizontal max-of-3 per pixel (includes center)
    float4 lr;  // horizontal max of left+right only (center excluded)
};

__device__ __forceinline__ HV rowmax(const float4 v, const int tx) {
    float l = __shfl_up(v.w, 1, 64);    // last elem of lane tx-1
    float r = __shfl_down(v.x, 1, 64);  // first elem of lane tx+1
    if (tx == 0)  l = v.x;              // replicate pad left edge
    if (tx == 63) r = v.w;              // replicate pad right edge
    HV o;
    o.h.x = fmaxf(l,   fmaxf(v.x, v.y));
    o.h.y = fmaxf(v.x, fmaxf(v.y, v.z));
    o.h.z = fmaxf(v.y, fmaxf(v.z, v.w));
    o.h.w = fmaxf(v.z, fmaxf(v.w, r));
    o.lr.x = fmaxf(l,   v.y);
    o.lr.y = fmaxf(v.x, v.z);
    o.lr.z = fmaxf(v.y, v.w);
    o.lr.w = fmaxf(v.z, r);
    return o;
}

__global__ __launch_bounds__(256) void nms2d_kernel(const float* __restrict__ x,
                                                    float* __restrict__ out) {
    // No XCD swizzle: default round-robin dispatch spreads each plane's
    // halo-amplified read traffic across all 8 XCDs; shared L3 (256 MB,
    // input fully resident) serves the cross-XCD halo re-reads.
    const int logical = blockIdx.x;

    const int plane_idx = logical >> 6;        // 512 planes
    const int rg        = logical & 63;        // 64 row-groups of 4 rows
    const int tx        = threadIdx.x & 63;    // float4 column-group
    const int r         = rg * 4 + (threadIdx.x >> 6);  // this wave's row
    const int col4      = tx * 4;

    const float* pl = x + (size_t)plane_idx * PLANE;

    // 3 independent clamped row loads — the thread's entire read set.
    const int rm = max(r - 1, 0);
    const int rp = min(r + 1, NMS_H - 1);
    const float4 va = *reinterpret_cast<const float4*>(pl + rm * NMS_W + col4);
    const float4 vc = *reinterpret_cast<const float4*>(pl + r  * NMS_W + col4);
    const float4 vb = *reinterpret_cast<const float4*>(pl + rp * NMS_W + col4);

    const HV ma = rowmax(va, tx);
    const HV mc = rowmax(vc, tx);
    const HV mb = rowmax(vb, tx);

    f4_t o;
    float m;
    m = fmaxf(0.0f, fmaxf(fmaxf(ma.h.x, mb.h.x), mc.lr.x)); o.x = (vc.x > m) ? vc.x : 0.0f;
    m = fmaxf(0.0f, fmaxf(fmaxf(ma.h.y, mb.h.y), mc.lr.y)); o.y = (vc.y > m) ? vc.y : 0.0f;
    m = fmaxf(0.0f, fmaxf(fmaxf(ma.h.z, mb.h.z), mc.lr.z)); o.z = (vc.z > m) ? vc.z : 0.0f;
    m = fmaxf(0.0f, fmaxf(fmaxf(ma.h.w, mb.h.w), mc.lr.w)); o.w = (vc.w > m) ? vc.w : 0.0f;

    *reinterpret_cast<f4_t*>(out + (size_t)plane_idx * PLANE + r * NMS_W + col4) = o;
}

extern "C" void kernel_launch(void* const* d_in, const int* in_sizes, int n_in,
                              void* d_out, int out_size, void* d_ws, size_t ws_size,
                              hipStream_t stream) {
    const float* x = (const float*)d_in[0];
    float* out = (float*)d_out;

    // One thread per output float4: 512 planes x 64 row-groups = 32768 blocks.
    dim3 block(256);
    dim3 grid(32768);
    nms2d_kernel<<<grid, block, 0, stream>>>(x, out);
}